// Round 3
// baseline (271.171 us; speedup 1.0000x reference)
//
#include <hip/hip_runtime.h>

// HierarchicalRouter: x[16384,2048] fp32, group_gate_w[8,2048], expert_gate_w[64,2048]
// out = concat(valid_mask[16384,64] as 0/1 float, normalized_weights[16384,64])
//
// R7: prep-presplit W (R6) + 64-token LDS-shared blocks (R4) + deep prefetch.
//  prep (640x256): splits W (80 gates = 64 expert + 8 group + 8 pad) into f16 h/l
//    (v = h + l/2048, exact fp32 reconstruction), CHUNK-CONTIGUOUS fragment layout:
//    [ks(64)][g(5)][pl(2)][slot(64)][j(8)] halfs -> each 64-k chunk of W is one dense
//    20480B blob -> router stages it into LDS as a linear 16B/lane copy. 640 KB in ws.
//  router (256x512): 64 tokens/block, 32 chunks of 64 k. Wave w=(tt=w>>1 token-tile,
//    s2=w&1 K-half); per chunk: 15 MFMA (mfma_f32_16x16x32_f16), 12 ds_read_b128.
//    LDS 75KB (W 2x20KB + x 2x16KB dbuf) -> 2 blocks/CU, 16 waves/CU: the two
//    blocks' barrier pipelines interleave. Per iter: barrier; issue W(c+1)+x(c+2)
//    loads (fly over compute, drain next barrier); compute(c); commit(c+1).
//    x is 2-deep (in-flight ~2 chunks > 900cy HBM latency); W is 1-deep (L2 ~250cy).
//    x LDS XOR-swizzle (slot ^= kslot) keeps ds_write/ds_read <=2-way; W fragments
//    read at lane*16 (conflict-free). logit = accH + accC/2048 (proven R4-R6 math).
//    Epilogue: 2-way K-reduce, softmax 8 tok/wave (proven fp32 code), coalesced stores.

#define NT 16384
#define NE 2048
#define NTH 512
#define NBLK 256
#define NCHUNK 32
#define WCH 20480
#define XCH 16384
#define XOFF 40960
#define LDS_BYTES 76800

typedef _Float16 v8h __attribute__((ext_vector_type(8)));
typedef float    v4f __attribute__((ext_vector_type(4)));

__global__ __launch_bounds__(256, 1)
void prep(const float* __restrict__ gw, const float* __restrict__ ew,
          _Float16* __restrict__ wf)
{
    const int t = blockIdx.x * 256 + threadIdx.x;   // 0..163839: one (ks,g,slot,j)
    const int j    = t & 7;
    const int sl   = (t >> 3) & 63;                 // slot = q*16 + m (A-fragment lane)
    const int rest = t >> 9;                        // 0..319
    const int g    = rest % 5;
    const int ks   = rest / 5;                      // 0..63 (32-float k-step)
    const int m = sl & 15, q = sl >> 4;
    const int gate = g * 16 + m;
    const int k = ks * 32 + q * 8 + j;
    float v = 0.f;
    if (gate < 64)      v = ew[gate * NE + k];
    else if (gate < 72) v = gw[(gate - 64) * NE + k];
    const _Float16 h = (_Float16)v;
    const int o = (((ks * 5 + g) * 2) * 64 + sl) * 8 + j;   // pl=0 plane
    wf[o]       = h;
    wf[o + 512] = (_Float16)((v - (float)h) * 2048.0f);     // pl=1 plane (+64 slots)
}

__global__ __launch_bounds__(NTH, 4)
void router(const float* __restrict__ x, const _Float16* __restrict__ wf,
            float* __restrict__ out)
{
    __shared__ __align__(16) char sm[LDS_BYTES];
    const int tid  = threadIdx.x;
    const int lane = tid & 63;
    const int w    = tid >> 6;
    const int tt   = w >> 1, s2 = w & 1;
    const int t0   = blockIdx.x * 64;

    // ---- x staging descriptor: thread -> (token = tid>>3, kslot = tid&7) ----
    const int xtok = tid >> 3, xks = tid & 7;
    const float* xsrc = x + (size_t)(t0 + xtok) * NE + xks * 8;
    // swizzled LDS addr (16B units), h plane; l plane = +64
    const int xa16 = (((xtok >> 4) * 2 + (xks >> 2)) * 2) * 64
                   + (((xks & 3) * 16 + (xtok & 15)) ^ xks);

    // ---- W copy descriptor: s = i*512 + tid (1280 x 16B per chunk) ----
    uint4  wr[3];
    float4 xr[2][2];

    auto wload = [&](int c) {
        const char* src = (const char*)wf + (size_t)c * WCH;
        wr[0] = *(const uint4*)(src + (0 * 512 + tid) * 16);
        wr[1] = *(const uint4*)(src + (1 * 512 + tid) * 16);
        if (tid < 256) wr[2] = *(const uint4*)(src + (1024 + tid) * 16);
    };
    auto wcommit = [&](int buf) {
        char* dst = sm + buf * WCH;
        *(uint4*)(dst + (0 * 512 + tid) * 16) = wr[0];
        *(uint4*)(dst + (1 * 512 + tid) * 16) = wr[1];
        if (tid < 256) *(uint4*)(dst + (1024 + tid) * 16) = wr[2];
    };
    auto xload = [&](int c) {
        const float* p = xsrc + c * 64;
        xr[c & 1][0] = *(const float4*)(p);
        xr[c & 1][1] = *(const float4*)(p + 4);
    };
    auto xcommit = [&](int c, int buf) {
        const float4 a = xr[c & 1][0], b = xr[c & 1][1];
        const float v[8] = {a.x, a.y, a.z, a.w, b.x, b.y, b.z, b.w};
        v8h h, l;
        #pragma unroll
        for (int j = 0; j < 8; ++j) {
            const _Float16 hh = (_Float16)v[j];
            h[j] = hh;
            l[j] = (_Float16)((v[j] - (float)hh) * 2048.0f);
        }
        char* xb = sm + XOFF + buf * XCH;
        *(v8h*)(xb + xa16 * 16)        = h;
        *(v8h*)(xb + (xa16 + 64) * 16) = l;
    };

    v4f accH[5], accC[5];
    #pragma unroll
    for (int g = 0; g < 5; ++g) { accH[g] = (v4f)(0.f); accC[g] = (v4f)(0.f); }

    // per-wave read offsets
    const int xrd = (((tt * 2 + s2) * 2) * 64 + (lane ^ (s2 * 4 + (lane >> 4)))) * 16;
    const int wrd = ((s2 * 5) * 2) * 1024 + lane * 16;

    // ---- prologue ----
    wload(0); xload(0);
    wcommit(0); xcommit(0, 0);
    xload(1);

    for (int c = 0; c < NCHUNK; ++c) {
        __syncthreads();                       // buf[c&1] published
        if (c + 1 < NCHUNK) wload(c + 1);      // fly over compute, drain next barrier
        if (c + 2 < NCHUNK) xload(c + 2);
        {
            const char* xb = sm + XOFF + (c & 1) * XCH;
            const char* wb = sm + (c & 1) * WCH;
            const v8h Bh = *(const v8h*)(xb + xrd);
            const v8h Bl = *(const v8h*)(xb + xrd + 1024);
            #pragma unroll
            for (int g = 0; g < 5; ++g) {
                const char* wpg = wb + wrd + g * 2048;
                const v8h Ah = *(const v8h*)(wpg);
                const v8h Al = *(const v8h*)(wpg + 1024);
                accH[g] = __builtin_amdgcn_mfma_f32_16x16x32_f16(Ah, Bh, accH[g], 0, 0, 0);
                accC[g] = __builtin_amdgcn_mfma_f32_16x16x32_f16(Ah, Bl, accC[g], 0, 0, 0);
                accC[g] = __builtin_amdgcn_mfma_f32_16x16x32_f16(Al, Bh, accC[g], 0, 0, 0);
            }
        }
        if (c + 1 < NCHUNK) { wcommit((c + 1) & 1); xcommit(c + 1, (c + 1) & 1); }
    }
    __syncthreads();

    // ---- exact recombine + 2-way K-reduce (across s2 halves) ----
    float part[5][4];
    #pragma unroll
    for (int g = 0; g < 5; ++g)
        #pragma unroll
        for (int r = 0; r < 4; ++r)
            part[g][r] = accH[g][r] + accC[g][r] * (1.0f / 2048.0f);

    float* red = (float*)sm;                       // [tt][g][r][lane] = 20480 B
    if (s2 == 1) {
        #pragma unroll
        for (int g = 0; g < 5; ++g)
            #pragma unroll
            for (int r = 0; r < 4; ++r)
                red[((tt * 5 + g) * 4 + r) * 64 + lane] = part[g][r];
    }
    __syncthreads();
    float* la = (float*)(sm + 20480);              // [64 tokens][84]
    if (s2 == 0) {
        #pragma unroll
        for (int g = 0; g < 5; ++g)
            #pragma unroll
            for (int r = 0; r < 4; ++r) {
                const float v = part[g][r] + red[((tt * 5 + g) * 4 + r) * 64 + lane];
                const int gate  = g * 16 + (lane >> 4) * 4 + r;   // D row = gate
                const int token = tt * 16 + (lane & 15);          // D col = token
                la[token * 84 + gate] = v;
            }
    }
    __syncthreads();

    // ---- per-token dual softmax + hierarchical mask (proven fp32), 8 tok/wave ----
    if (lane < 8) {
        const int token = w * 8 + lane;
        const float* lg = la + token * 84;          // [0..63]=experts, [64..71]=groups
        float* M  = (float*)(sm + 41984) + token * 64;
        float* Wn = (float*)(sm + 58368) + token * 64;

        float gpb[8];
        float gmax = lg[64];
        #pragma unroll
        for (int g = 1; g < 8; ++g) gmax = fmaxf(gmax, lg[64 + g]);
        float gsum = 0.f;
        #pragma unroll
        for (int g = 0; g < 8; ++g) { gpb[g] = __expf(lg[64 + g] - gmax); gsum += gpb[g]; }
        const float ginv = 1.f / gsum;

        float sel[64];
        float wsum = 0.f;
        #pragma unroll
        for (int g = 0; g < 8; ++g) {
            const float gp_ = gpb[g] * ginv;
            float emax = lg[g * 8];
            #pragma unroll
            for (int j = 1; j < 8; ++j) emax = fmaxf(emax, lg[g * 8 + j]);
            float ep[8]; float esum = 0.f;
            #pragma unroll
            for (int j = 0; j < 8; ++j) { ep[j] = __expf(lg[g * 8 + j] - emax); esum += ep[j]; }
            const float einv = 1.f / esum;
            const bool gm = gp_ >= 0.125f;
            #pragma unroll
            for (int j = 0; j < 8; ++j) {
                const float pe = ep[j] * einv;
                const bool v = gm && (pe >= 0.125f);
                const float ww = v ? gp_ * pe : 0.f;
                M[g * 8 + j] = v ? 1.f : 0.f;
                sel[g * 8 + j] = ww;
                wsum += ww;
            }
        }
        const float inv = 1.f / fmaxf(wsum, 1e-9f);
        #pragma unroll
        for (int e = 0; e < 64; ++e) Wn[e] = sel[e] * inv;
    }
    __syncthreads();

    // ---- coalesced stores: 64 tokens x 64 = 1024 float4 per tensor ----
    const float4* M4 = (const float4*)(sm + 41984);
    const float4* W4 = (const float4*)(sm + 58368);
    float4* o0 = (float4*)(out + (size_t)t0 * 64);
    float4* o1 = (float4*)(out + (size_t)NT * 64 + (size_t)t0 * 64);
    o0[tid]       = M4[tid];
    o0[tid + 512] = M4[tid + 512];
    o1[tid]       = W4[tid];
    o1[tid + 512] = W4[tid + 512];
}

extern "C" void kernel_launch(void* const* d_in, const int* in_sizes, int n_in,
                              void* d_out, int out_size, void* d_ws, size_t ws_size,
                              hipStream_t stream) {
    const float* x  = (const float*)d_in[0];
    const float* gw = (const float*)d_in[1];
    const float* ew = (const float*)d_in[2];
    float* out = (float*)d_out;
    _Float16* wf = (_Float16*)d_ws;
    (void)ws_size; (void)in_sizes; (void)n_in; (void)out_size;

    prep<<<dim3(640), dim3(256), 0, stream>>>(gw, ew, wf);
    router<<<dim3(NBLK), dim3(NTH), 0, stream>>>(x, wf, out);
}

// Round 4
// 209.305 us; speedup vs baseline: 1.2956x; 1.2956x over previous
//
#include <hip/hip_runtime.h>

// HierarchicalRouter: x[16384,2048] fp32, group_gate_w[8,2048], expert_gate_w[64,2048]
// out = concat(valid_mask[16384,64] as 0/1 float, normalized_weights[16384,64])
//
// R8 = R7 with the scratch-demotion bug fixed (rule #20):
//  R7's xr[c&1] runtime-indexed register array was demoted to scratch (VGPR=52,
//  WRITE_SIZE=96MB, 131us). Fix: chunk loop unrolled by 2 with NAMED x-prefetch
//  register pairs (xA0/xA1, xB0/xB1) passed by reference -> all reg accesses are
//  compile-time -> stays in VGPRs. launch_bounds(512,2) (grid=256 -> 1 block/CU
//  anyway; give the allocator 256-reg headroom).
//
//  prep (640x256): splits W (80 gates = 64 expert + 8 group + 8 pad) into f16 h/l
//    (v = h + l/2048, exact fp32 reconstruction), chunk-contiguous fragment layout:
//    [ks(64)][g(5)][pl(2)][slot(64)][j(8)] halfs; each 64-k chunk = dense 20480B blob.
//  router (256x512): 64 tokens/block, 32 chunks of 64 k. Wave w=(tt=w>>1 token-tile,
//    s2=w&1 K-half); per chunk: 15 mfma_f32_16x16x32_f16, 12 ds_read_b128.
//    Per iter: barrier; issue W(c+1)+x(c+2) loads (fly over compute, drain at commit);
//    compute(c); commit(c+1). x 2-deep (covers ~900cy HBM), W 1-deep (L2).
//    x LDS XOR-swizzle keeps ds_write/ds_read <=2-way; W read at lane*16 (clean).
//    logit = accH + accC/2048 (proven exact-split math). Epilogue: 2-way K-reduce,
//    softmax 8 tok/wave (proven fp32 code), coalesced stores.

#define NT 16384
#define NE 2048
#define NTH 512
#define NBLK 256
#define NCHUNK 32
#define WCH 20480
#define XCH 16384
#define XOFF 40960
#define LDS_BYTES 76800

typedef _Float16 v8h __attribute__((ext_vector_type(8)));
typedef float    v4f __attribute__((ext_vector_type(4)));

__global__ __launch_bounds__(256, 1)
void prep(const float* __restrict__ gw, const float* __restrict__ ew,
          _Float16* __restrict__ wf)
{
    const int t = blockIdx.x * 256 + threadIdx.x;   // 0..163839: one (ks,g,slot,j)
    const int j    = t & 7;
    const int sl   = (t >> 3) & 63;                 // slot = q*16 + m (A-fragment lane)
    const int rest = t >> 9;                        // 0..319
    const int g    = rest % 5;
    const int ks   = rest / 5;                      // 0..63 (32-float k-step)
    const int m = sl & 15, q = sl >> 4;
    const int gate = g * 16 + m;
    const int k = ks * 32 + q * 8 + j;
    float v = 0.f;
    if (gate < 64)      v = ew[gate * NE + k];
    else if (gate < 72) v = gw[(gate - 64) * NE + k];
    const _Float16 h = (_Float16)v;
    const int o = (((ks * 5 + g) * 2) * 64 + sl) * 8 + j;   // pl=0 plane
    wf[o]       = h;
    wf[o + 512] = (_Float16)((v - (float)h) * 2048.0f);     // pl=1 plane (+64 slots)
}

__global__ __launch_bounds__(NTH, 2)
void router(const float* __restrict__ x, const _Float16* __restrict__ wf,
            float* __restrict__ out)
{
    __shared__ __align__(16) char sm[LDS_BYTES];
    const int tid  = threadIdx.x;
    const int lane = tid & 63;
    const int w    = tid >> 6;
    const int tt   = w >> 1, s2 = w & 1;
    const int t0   = blockIdx.x * 64;

    // ---- x staging descriptor: thread -> (token = tid>>3, kslot = tid&7) ----
    const int xtok = tid >> 3, xks = tid & 7;
    const float* xsrc = x + (size_t)(t0 + xtok) * NE + xks * 8;
    // swizzled LDS addr (16B units), h plane; l plane = +64
    const int xa16 = (((xtok >> 4) * 2 + (xks >> 2)) * 2) * 64
                   + (((xks & 3) * 16 + (xtok & 15)) ^ xks);

    uint4 wr0, wr1, wr2;

    auto wload = [&](int c) {
        const char* src = (const char*)wf + (size_t)c * WCH;
        wr0 = *(const uint4*)(src + (0 * 512 + tid) * 16);
        wr1 = *(const uint4*)(src + (1 * 512 + tid) * 16);
        if (tid < 256) wr2 = *(const uint4*)(src + (1024 + tid) * 16);
    };
    auto wcommit = [&](int buf) {
        char* dst = sm + buf * WCH;
        *(uint4*)(dst + (0 * 512 + tid) * 16) = wr0;
        *(uint4*)(dst + (1 * 512 + tid) * 16) = wr1;
        if (tid < 256) *(uint4*)(dst + (1024 + tid) * 16) = wr2;
    };
    auto xload_to = [&](int c, float4& r0, float4& r1) {
        const float* p = xsrc + c * 64;
        r0 = *(const float4*)(p);
        r1 = *(const float4*)(p + 4);
    };
    auto xcommit_from = [&](const float4& a, const float4& b, int buf) {
        const float v[8] = {a.x, a.y, a.z, a.w, b.x, b.y, b.z, b.w};
        v8h h, l;
        #pragma unroll
        for (int j = 0; j < 8; ++j) {
            const _Float16 hh = (_Float16)v[j];
            h[j] = hh;
            l[j] = (_Float16)((v[j] - (float)hh) * 2048.0f);
        }
        char* xb = sm + XOFF + buf * XCH;
        *(v8h*)(xb + xa16 * 16)        = h;
        *(v8h*)(xb + (xa16 + 64) * 16) = l;
    };

    v4f accH[5], accC[5];
    #pragma unroll
    for (int g = 0; g < 5; ++g) { accH[g] = (v4f)(0.f); accC[g] = (v4f)(0.f); }

    // per-wave read offsets
    const int xrd = (((tt * 2 + s2) * 2) * 64 + (lane ^ (s2 * 4 + (lane >> 4)))) * 16;
    const int wrd = ((s2 * 5) * 2) * 1024 + lane * 16;

    auto compute = [&](int P) {      // P = chunk parity (compile-time at call sites)
        const char* xb = sm + XOFF + P * XCH;
        const char* wb = sm + P * WCH;
        const v8h Bh = *(const v8h*)(xb + xrd);
        const v8h Bl = *(const v8h*)(xb + xrd + 1024);
        #pragma unroll
        for (int g = 0; g < 5; ++g) {
            const char* wpg = wb + wrd + g * 2048;
            const v8h Ah = *(const v8h*)(wpg);
            const v8h Al = *(const v8h*)(wpg + 1024);
            accH[g] = __builtin_amdgcn_mfma_f32_16x16x32_f16(Ah, Bh, accH[g], 0, 0, 0);
            accC[g] = __builtin_amdgcn_mfma_f32_16x16x32_f16(Ah, Bl, accC[g], 0, 0, 0);
            accC[g] = __builtin_amdgcn_mfma_f32_16x16x32_f16(Al, Bh, accC[g], 0, 0, 0);
        }
    };

    // named x-prefetch buffers: parity-0 chunks live in A, parity-1 in B (rule #20:
    // every access compile-time -> VGPRs, never scratch)
    float4 xA0, xA1, xB0, xB1;

    // ---- prologue ----
    wload(0);
    xload_to(0, xA0, xA1);
    wcommit(0);
    xcommit_from(xA0, xA1, 0);
    xload_to(1, xB0, xB1);

    // step(c): barrier; wload(c+1); xload(c+2)->cur; compute(c); wcommit; xcommit(prev)
    auto step = [&](int c, int P, float4& cur0, float4& cur1,
                    const float4& prv0, const float4& prv1) {
        __syncthreads();                        // buf[P] published
        if (c + 1 < NCHUNK) wload(c + 1);
        if (c + 2 < NCHUNK) xload_to(c + 2, cur0, cur1);
        compute(P);
        if (c + 1 < NCHUNK) { wcommit(1 - P); xcommit_from(prv0, prv1, 1 - P); }
    };

    #pragma unroll 1
    for (int cc = 0; cc < NCHUNK; cc += 2) {
        step(cc,     0, xA0, xA1, xB0, xB1);    // loads chunk cc+2 into A, commits cc+1 from B
        step(cc + 1, 1, xB0, xB1, xA0, xA1);    // loads chunk cc+3 into B, commits cc+2 from A
    }
    __syncthreads();

    // ---- exact recombine + 2-way K-reduce (across s2 halves) ----
    float part[5][4];
    #pragma unroll
    for (int g = 0; g < 5; ++g)
        #pragma unroll
        for (int r = 0; r < 4; ++r)
            part[g][r] = accH[g][r] + accC[g][r] * (1.0f / 2048.0f);

    float* red = (float*)sm;                       // [tt][g][r][lane] = 20480 B
    if (s2 == 1) {
        #pragma unroll
        for (int g = 0; g < 5; ++g)
            #pragma unroll
            for (int r = 0; r < 4; ++r)
                red[((tt * 5 + g) * 4 + r) * 64 + lane] = part[g][r];
    }
    __syncthreads();
    float* la = (float*)(sm + 20480);              // [64 tokens][84]
    if (s2 == 0) {
        #pragma unroll
        for (int g = 0; g < 5; ++g)
            #pragma unroll
            for (int r = 0; r < 4; ++r) {
                const float v = part[g][r] + red[((tt * 5 + g) * 4 + r) * 64 + lane];
                const int gate  = g * 16 + (lane >> 4) * 4 + r;   // D row = gate
                const int token = tt * 16 + (lane & 15);          // D col = token
                la[token * 84 + gate] = v;
            }
    }
    __syncthreads();

    // ---- per-token dual softmax + hierarchical mask (proven fp32), 8 tok/wave ----
    if (lane < 8) {
        const int token = w * 8 + lane;
        const float* lg = la + token * 84;          // [0..63]=experts, [64..71]=groups
        float* M  = (float*)(sm + 41984) + token * 64;
        float* Wn = (float*)(sm + 58368) + token * 64;

        float gpb[8];
        float gmax = lg[64];
        #pragma unroll
        for (int g = 1; g < 8; ++g) gmax = fmaxf(gmax, lg[64 + g]);
        float gsum = 0.f;
        #pragma unroll
        for (int g = 0; g < 8; ++g) { gpb[g] = __expf(lg[64 + g] - gmax); gsum += gpb[g]; }
        const float ginv = 1.f / gsum;

        float sel[64];
        float wsum = 0.f;
        #pragma unroll
        for (int g = 0; g < 8; ++g) {
            const float gp_ = gpb[g] * ginv;
            float emax = lg[g * 8];
            #pragma unroll
            for (int j = 1; j < 8; ++j) emax = fmaxf(emax, lg[g * 8 + j]);
            float ep[8]; float esum = 0.f;
            #pragma unroll
            for (int j = 0; j < 8; ++j) { ep[j] = __expf(lg[g * 8 + j] - emax); esum += ep[j]; }
            const float einv = 1.f / esum;
            const bool gm = gp_ >= 0.125f;
            #pragma unroll
            for (int j = 0; j < 8; ++j) {
                const float pe = ep[j] * einv;
                const bool v = gm && (pe >= 0.125f);
                const float ww = v ? gp_ * pe : 0.f;
                M[g * 8 + j] = v ? 1.f : 0.f;
                sel[g * 8 + j] = ww;
                wsum += ww;
            }
        }
        const float inv = 1.f / fmaxf(wsum, 1e-9f);
        #pragma unroll
        for (int e = 0; e < 64; ++e) Wn[e] = sel[e] * inv;
    }
    __syncthreads();

    // ---- coalesced stores: 64 tokens x 64 = 1024 float4 per tensor ----
    const float4* M4 = (const float4*)(sm + 41984);
    const float4* W4 = (const float4*)(sm + 58368);
    float4* o0 = (float4*)(out + (size_t)t0 * 64);
    float4* o1 = (float4*)(out + (size_t)NT * 64 + (size_t)t0 * 64);
    o0[tid]       = M4[tid];
    o0[tid + 512] = M4[tid + 512];
    o1[tid]       = W4[tid];
    o1[tid + 512] = W4[tid + 512];
}

extern "C" void kernel_launch(void* const* d_in, const int* in_sizes, int n_in,
                              void* d_out, int out_size, void* d_ws, size_t ws_size,
                              hipStream_t stream) {
    const float* x  = (const float*)d_in[0];
    const float* gw = (const float*)d_in[1];
    const float* ew = (const float*)d_in[2];
    float* out = (float*)d_out;
    _Float16* wf = (_Float16*)d_ws;
    (void)ws_size; (void)in_sizes; (void)n_in; (void)out_size;

    prep<<<dim3(640), dim3(256), 0, stream>>>(gw, ew, wf);
    router<<<dim3(NBLK), dim3(NTH), 0, stream>>>(x, wf, out);
}